// Round 2
// baseline (63.921 us; speedup 1.0000x reference)
//
#include <hip/hip_runtime.h>
#include <math.h>

#define H 2048
#define Wd 256
#define DEPTH 1024
#define V 128

// ws float layout:
//  [0..2]   : a_push, a_pop, a_noop (softmaxed ctrl)
//  [4..259] : stack_in[256]
//  [320..2623] : rnn_in[2304]  (2048 emb || 256 stack_top)
//  [4096..20479] : g[16384]  (fwd 8192, bwd 8192)
#define WS_A      0
#define WS_SIN    4
#define WS_RNNIN  320
#define WS_G      4096

__device__ __forceinline__ float wave_reduce(float v) {
    #pragma unroll
    for (int off = 32; off; off >>= 1) v += __shfl_xor(v, off, 64);
    return v;
}

__device__ __forceinline__ float sigm(float x) { return 1.f / (1.f + expf(-x)); }

// Kernel 1: ctrl (3x4096 matvec + softmax) and stack_in (256x4096 matvec + tanh)
__global__ void k1_ctrl_stackin(const float* __restrict__ hidden,
                                const float* __restrict__ W_ctrl, const float* __restrict__ b_ctrl,
                                const float* __restrict__ W_sin, const float* __restrict__ b_sin,
                                float* __restrict__ ws) {
    const int b = blockIdx.x;
    const float4* hv = (const float4*)hidden;   // 1024 float4 = h2s (concat of hidden[0],hidden[1])
    if (b == 0) {
        __shared__ float dots[3];
        const int wave = threadIdx.x >> 6;
        const int lane = threadIdx.x & 63;
        if (wave < 3) {
            const float4* Wr = (const float4*)(W_ctrl + wave * (2 * H));
            float acc = 0.f;
            for (int k = lane; k < 1024; k += 64) {
                float4 w4 = Wr[k], h4 = hv[k];
                acc += w4.x * h4.x + w4.y * h4.y + w4.z * h4.z + w4.w * h4.w;
            }
            acc = wave_reduce(acc);
            if (lane == 0) dots[wave] = acc + b_ctrl[wave];
        }
        __syncthreads();
        if (threadIdx.x == 0) {
            float m = fmaxf(dots[0], fmaxf(dots[1], dots[2]));
            float e0 = expf(dots[0] - m), e1 = expf(dots[1] - m), e2 = expf(dots[2] - m);
            float s = e0 + e1 + e2;
            ws[WS_A + 0] = e0 / s;  // a_push
            ws[WS_A + 1] = e1 / s;  // a_pop
            ws[WS_A + 2] = e2 / s;  // a_noop
        }
    } else {
        const int r = b - 1;  // 0..255
        const float4* Wr = (const float4*)(W_sin + (size_t)r * (2 * H));
        float acc = 0.f;
        for (int k = threadIdx.x; k < 1024; k += 256) {
            float4 w4 = Wr[k], h4 = hv[k];
            acc += w4.x * h4.x + w4.y * h4.y + w4.z * h4.z + w4.w * h4.w;
        }
        __shared__ float red[4];
        acc = wave_reduce(acc);
        const int wave = threadIdx.x >> 6, lane = threadIdx.x & 63;
        if (lane == 0) red[wave] = acc;
        __syncthreads();
        if (threadIdx.x == 0) {
            float s = red[0] + red[1] + red[2] + red[3] + b_sin[r];
            ws[WS_SIN + r] = tanhf(s);
        }
    }
}

// Kernel 2: stack update (writes new_stack to d_out) + build rnn_in in ws
__global__ void k2_stack(const float* __restrict__ stack,
                         const float* __restrict__ emb, const int* __restrict__ inp,
                         const float* __restrict__ ws_in,
                         float* __restrict__ new_stack, float* __restrict__ rnn_in) {
    const int b = blockIdx.x;
    if (b < DEPTH) {
        const int d = b;
        const int w = threadIdx.x;  // 256 threads
        const float a_push = ws_in[WS_A + 0];
        const float a_pop  = ws_in[WS_A + 1];
        const float a_noop = ws_in[WS_A + 2];
        const float cur  = stack[d * Wd + w];
        const float up   = (d == 0) ? ws_in[WS_SIN + w] : stack[(d - 1) * Wd + w];
        const float down = (d == DEPTH - 1) ? 0.f : stack[(d + 1) * Wd + w];
        const float nv = a_noop * cur + a_push * up + a_pop * down;
        new_stack[d * Wd + w] = nv;
        if (d == 0) rnn_in[H + w] = nv;   // stack_top
    } else {
        const int j = (b - DEPTH) * 256 + threadIdx.x;  // 0..2047
        rnn_in[j] = emb[(size_t)inp[0] * H + j];
    }
}

// Kernel 3: LSTM gate matvecs, both directions. One wave per output row.
// Register-staged: all 17 weight float4 loads issued before accumulation to
// maximize per-wave memory-level parallelism (VGPR_Count=20 last round showed
// the compiler was holding only ~2 loads in flight).
__global__ void __launch_bounds__(256) k3_gates(
        const float* __restrict__ rnn_in, const float* __restrict__ hidden,
        const float* __restrict__ w_ih_f, const float* __restrict__ w_hh_f,
        const float* __restrict__ b_ih_f, const float* __restrict__ b_hh_f,
        const float* __restrict__ w_ih_b, const float* __restrict__ w_hh_b,
        const float* __restrict__ b_ih_b, const float* __restrict__ b_hh_b,
        float* __restrict__ g) {
    const int r = (blockIdx.x * blockDim.x + threadIdx.x) >> 6;  // 0..16383
    const int lane = threadIdx.x & 63;
    const float* wih; const float* whh; const float* bih; const float* bhh;
    const float* h; int row;
    if (r < 4 * H) { wih = w_ih_f; whh = w_hh_f; bih = b_ih_f; bhh = b_hh_f; h = hidden;      row = r; }
    else           { wih = w_ih_b; whh = w_hh_b; bih = b_ih_b; bhh = b_hh_b; h = hidden + H; row = r - 4 * H; }

    const float4* wi = (const float4*)(wih + (size_t)row * (H + Wd));
    const float4* wh = (const float4*)(whh + (size_t)row * H);
    const float4* xi = (const float4*)rnn_in;
    const float4* hv = (const float4*)h;

    // Issue ALL streaming weight loads first (17 float4 in flight per lane).
    float4 w[9], u[8];
    #pragma unroll
    for (int k = 0; k < 9; ++k) w[k] = wi[lane + 64 * k];
    #pragma unroll
    for (int k = 0; k < 8; ++k) u[k] = wh[lane + 64 * k];

    float acc = 0.f;
    #pragma unroll
    for (int k = 0; k < 9; ++k) {   // 576 float4 = 2304 floats
        float4 x4 = xi[lane + 64 * k];
        acc += w[k].x * x4.x + w[k].y * x4.y + w[k].z * x4.z + w[k].w * x4.w;
    }
    #pragma unroll
    for (int k = 0; k < 8; ++k) {   // 512 float4 = 2048 floats
        float4 h4 = hv[lane + 64 * k];
        acc += u[k].x * h4.x + u[k].y * h4.y + u[k].z * h4.z + u[k].w * h4.w;
    }
    acc = wave_reduce(acc);
    if (lane == 0) g[r] = acc + bih[row] + bhh[row];
}

// Kernel 4: gate nonlinearity -> new_hidden, new_cell (into d_out)
__global__ void k4_hc(const float* __restrict__ g, const float* __restrict__ cell,
                      float* __restrict__ out) {
    const int t = blockIdx.x * blockDim.x + threadIdx.x;  // 0..4095
    const int dir = t >> 11, j = t & (H - 1);
    const float* gd = g + dir * 4 * H;
    const float iv = gd[j], fv = gd[H + j], gv = gd[2 * H + j], ov = gd[3 * H + j];
    const float c_old = cell[dir * H + j];
    const float c2 = sigm(fv) * c_old + sigm(iv) * tanhf(gv);
    const float h2 = sigm(ov) * tanhf(c2);
    out[V + dir * H + j] = h2;             // new_hidden
    out[V + 2 * H + dir * H + j] = c2;     // new_cell
}

// Kernel 5: decoder logits = W_dec @ [h_f,h_b] + b_dec. One wave per row.
__global__ void k5_dec(const float* __restrict__ out_h, const float* __restrict__ W_dec,
                       const float* __restrict__ b_dec, float* __restrict__ logits) {
    const int r = (blockIdx.x * blockDim.x + threadIdx.x) >> 6;  // 0..127
    const int lane = threadIdx.x & 63;
    const float4* Wr = (const float4*)(W_dec + (size_t)r * (2 * H));
    const float4* hv = (const float4*)out_h;
    float4 w[16];
    #pragma unroll
    for (int k = 0; k < 16; ++k) w[k] = Wr[lane + 64 * k];
    float acc = 0.f;
    #pragma unroll
    for (int k = 0; k < 16; ++k) {  // 1024 float4 = 4096 floats
        float4 h4 = hv[lane + 64 * k];
        acc += w[k].x * h4.x + w[k].y * h4.y + w[k].z * h4.z + w[k].w * h4.w;
    }
    acc = wave_reduce(acc);
    if (lane == 0) logits[r] = acc + b_dec[r];
}

extern "C" void kernel_launch(void* const* d_in, const int* in_sizes, int n_in,
                              void* d_out, int out_size, void* d_ws, size_t ws_size,
                              hipStream_t stream) {
    const int*   inp    = (const int*)  d_in[0];
    const float* hidden = (const float*)d_in[1];
    const float* cell   = (const float*)d_in[2];
    const float* stack  = (const float*)d_in[3];
    const float* emb    = (const float*)d_in[4];
    const float* W_ctrl = (const float*)d_in[5];
    const float* b_ctrl = (const float*)d_in[6];
    const float* W_sin  = (const float*)d_in[7];
    const float* b_sin  = (const float*)d_in[8];
    const float* w_ih_f = (const float*)d_in[9];
    const float* w_hh_f = (const float*)d_in[10];
    const float* b_ih_f = (const float*)d_in[11];
    const float* b_hh_f = (const float*)d_in[12];
    const float* w_ih_b = (const float*)d_in[13];
    const float* w_hh_b = (const float*)d_in[14];
    const float* b_ih_b = (const float*)d_in[15];
    const float* b_hh_b = (const float*)d_in[16];
    const float* W_dec  = (const float*)d_in[17];
    const float* b_dec  = (const float*)d_in[18];

    float* out = (float*)d_out;
    float* ws  = (float*)d_ws;

    float* new_stack = out + V + 4 * H;      // offset 8320
    float* rnn_in    = ws + WS_RNNIN;
    float* g         = ws + WS_G;

    // K1: ctrl + stack_in
    k1_ctrl_stackin<<<257, 256, 0, stream>>>(hidden, W_ctrl, b_ctrl, W_sin, b_sin, ws);
    // K2: stack update + rnn_in assembly (1024 stack blocks + 8 emb blocks)
    k2_stack<<<DEPTH + 8, 256, 0, stream>>>(stack, emb, inp, ws, new_stack, rnn_in);
    // K3: gate matvecs, 16384 rows, 1 wave/row, 4 waves/block
    k3_gates<<<4096, 256, 0, stream>>>(rnn_in, hidden,
                                       w_ih_f, w_hh_f, b_ih_f, b_hh_f,
                                       w_ih_b, w_hh_b, b_ih_b, b_hh_b, g);
    // K4: h/c elementwise
    k4_hc<<<16, 256, 0, stream>>>(g, cell, out);
    // K5: decoder, 128 rows, 1 wave/row
    k5_dec<<<32, 256, 0, stream>>>(out + V, W_dec, b_dec, out);
}

// Round 3
// 62.099 us; speedup vs baseline: 1.0293x; 1.0293x over previous
//
#include <hip/hip_runtime.h>
#include <math.h>

#define H 2048
#define Wd 256
#define DEPTH 1024
#define V 128

// ws float layout:
//  [0..2]   : a_push, a_pop, a_noop (softmaxed ctrl)
//  [4..259] : stack_in[256]
//  [320..2623] : rnn_in[2304]  (2048 emb || 256 stack_top)
#define WS_A      0
#define WS_SIN    4
#define WS_RNNIN  320

__device__ __forceinline__ float wave_reduce(float v) {
    #pragma unroll
    for (int off = 32; off; off >>= 1) v += __shfl_xor(v, off, 64);
    return v;
}

__device__ __forceinline__ float sigm(float x) { return 1.f / (1.f + expf(-x)); }

// Kernel 1: ctrl (3x4096 matvec + softmax) and stack_in (256x4096 matvec + tanh)
__global__ void k1_ctrl_stackin(const float* __restrict__ hidden,
                                const float* __restrict__ W_ctrl, const float* __restrict__ b_ctrl,
                                const float* __restrict__ W_sin, const float* __restrict__ b_sin,
                                float* __restrict__ ws) {
    const int b = blockIdx.x;
    const float4* hv = (const float4*)hidden;   // 1024 float4 = h2s (concat of hidden[0],hidden[1])
    if (b == 0) {
        __shared__ float dots[3];
        const int wave = threadIdx.x >> 6;
        const int lane = threadIdx.x & 63;
        if (wave < 3) {
            const float4* Wr = (const float4*)(W_ctrl + wave * (2 * H));
            float acc = 0.f;
            for (int k = lane; k < 1024; k += 64) {
                float4 w4 = Wr[k], h4 = hv[k];
                acc += w4.x * h4.x + w4.y * h4.y + w4.z * h4.z + w4.w * h4.w;
            }
            acc = wave_reduce(acc);
            if (lane == 0) dots[wave] = acc + b_ctrl[wave];
        }
        __syncthreads();
        if (threadIdx.x == 0) {
            float m = fmaxf(dots[0], fmaxf(dots[1], dots[2]));
            float e0 = expf(dots[0] - m), e1 = expf(dots[1] - m), e2 = expf(dots[2] - m);
            float s = e0 + e1 + e2;
            ws[WS_A + 0] = e0 / s;  // a_push
            ws[WS_A + 1] = e1 / s;  // a_pop
            ws[WS_A + 2] = e2 / s;  // a_noop
        }
    } else {
        const int r = b - 1;  // 0..255
        const float4* Wr = (const float4*)(W_sin + (size_t)r * (2 * H));
        float acc = 0.f;
        for (int k = threadIdx.x; k < 1024; k += 256) {
            float4 w4 = Wr[k], h4 = hv[k];
            acc += w4.x * h4.x + w4.y * h4.y + w4.z * h4.z + w4.w * h4.w;
        }
        __shared__ float red[4];
        acc = wave_reduce(acc);
        const int wave = threadIdx.x >> 6, lane = threadIdx.x & 63;
        if (lane == 0) red[wave] = acc;
        __syncthreads();
        if (threadIdx.x == 0) {
            float s = red[0] + red[1] + red[2] + red[3] + b_sin[r];
            ws[WS_SIN + r] = tanhf(s);
        }
    }
}

// Kernel 2: stack update (writes new_stack to d_out) + build rnn_in in ws
__global__ void k2_stack(const float* __restrict__ stack,
                         const float* __restrict__ emb, const int* __restrict__ inp,
                         const float* __restrict__ ws_in,
                         float* __restrict__ new_stack, float* __restrict__ rnn_in) {
    const int b = blockIdx.x;
    if (b < DEPTH) {
        const int d = b;
        const int w = threadIdx.x;  // 256 threads
        const float a_push = ws_in[WS_A + 0];
        const float a_pop  = ws_in[WS_A + 1];
        const float a_noop = ws_in[WS_A + 2];
        const float cur  = stack[d * Wd + w];
        const float up   = (d == 0) ? ws_in[WS_SIN + w] : stack[(d - 1) * Wd + w];
        const float down = (d == DEPTH - 1) ? 0.f : stack[(d + 1) * Wd + w];
        const float nv = a_noop * cur + a_push * up + a_pop * down;
        new_stack[d * Wd + w] = nv;
        if (d == 0) rnn_in[H + w] = nv;   // stack_top
    } else {
        const int j = (b - DEPTH) * 256 + threadIdx.x;  // 0..2047
        rnn_in[j] = emb[(size_t)inp[0] * H + j];
    }
}

// Kernel 3: fused LSTM. One wave per (dir, hidden unit): computes all 4 gate
// dot products (sharing the x/h vector loads 4-ways -> halves total VMEM
// instruction count, 4 independent acc chains for MLP), then applies the
// gate nonlinearity in the epilogue (k4 fused away; g never materializes).
__global__ void __launch_bounds__(256) k3_lstm(
        const float* __restrict__ rnn_in, const float* __restrict__ hidden,
        const float* __restrict__ cell,
        const float* __restrict__ w_ih_f, const float* __restrict__ w_hh_f,
        const float* __restrict__ b_ih_f, const float* __restrict__ b_hh_f,
        const float* __restrict__ w_ih_b, const float* __restrict__ w_hh_b,
        const float* __restrict__ b_ih_b, const float* __restrict__ b_hh_b,
        float* __restrict__ out) {
    const int wid = (blockIdx.x * blockDim.x + threadIdx.x) >> 6;  // 0..4095
    const int lane = threadIdx.x & 63;
    const int dir = wid >> 11;          // 0 = fwd, 1 = bwd
    const int unit = wid & (H - 1);     // 0..2047

    const float* wih = dir ? w_ih_b : w_ih_f;
    const float* whh = dir ? w_hh_b : w_hh_f;
    const float* bih = dir ? b_ih_b : b_ih_f;
    const float* bhh = dir ? b_hh_b : b_hh_f;
    const float* h = hidden + dir * H;

    const float4* xi = (const float4*)rnn_in;
    const float4* hv = (const float4*)h;

    const float4* wi_i = (const float4*)wih + (size_t)unit * 576;
    const float4* wi_f = (const float4*)wih + (size_t)(H + unit) * 576;
    const float4* wi_g = (const float4*)wih + (size_t)(2 * H + unit) * 576;
    const float4* wi_o = (const float4*)wih + (size_t)(3 * H + unit) * 576;
    const float4* wh_i = (const float4*)whh + (size_t)unit * 512;
    const float4* wh_f = (const float4*)whh + (size_t)(H + unit) * 512;
    const float4* wh_g = (const float4*)whh + (size_t)(2 * H + unit) * 512;
    const float4* wh_o = (const float4*)whh + (size_t)(3 * H + unit) * 512;

    float ai = 0.f, af = 0.f, ag = 0.f, ao = 0.f;
    #pragma unroll
    for (int k = 0; k < 9; ++k) {       // 576 float4 = 2304 floats (x part)
        const int idx = lane + 64 * k;
        const float4 x4 = xi[idx];
        const float4 a = wi_i[idx], b = wi_f[idx], c = wi_g[idx], d = wi_o[idx];
        ai += a.x * x4.x + a.y * x4.y + a.z * x4.z + a.w * x4.w;
        af += b.x * x4.x + b.y * x4.y + b.z * x4.z + b.w * x4.w;
        ag += c.x * x4.x + c.y * x4.y + c.z * x4.z + c.w * x4.w;
        ao += d.x * x4.x + d.y * x4.y + d.z * x4.z + d.w * x4.w;
    }
    #pragma unroll
    for (int k = 0; k < 8; ++k) {       // 512 float4 = 2048 floats (h part)
        const int idx = lane + 64 * k;
        const float4 h4 = hv[idx];
        const float4 a = wh_i[idx], b = wh_f[idx], c = wh_g[idx], d = wh_o[idx];
        ai += a.x * h4.x + a.y * h4.y + a.z * h4.z + a.w * h4.w;
        af += b.x * h4.x + b.y * h4.y + b.z * h4.z + b.w * h4.w;
        ag += c.x * h4.x + c.y * h4.y + c.z * h4.z + c.w * h4.w;
        ao += d.x * h4.x + d.y * h4.y + d.z * h4.z + d.w * h4.w;
    }

    ai = wave_reduce(ai);
    af = wave_reduce(af);
    ag = wave_reduce(ag);
    ao = wave_reduce(ao);

    if (lane == 0) {
        const float gi = ai + bih[unit]         + bhh[unit];
        const float gf = af + bih[H + unit]     + bhh[H + unit];
        const float gg = ag + bih[2 * H + unit] + bhh[2 * H + unit];
        const float go = ao + bih[3 * H + unit] + bhh[3 * H + unit];
        const float c_old = cell[dir * H + unit];
        const float c2 = sigm(gf) * c_old + sigm(gi) * tanhf(gg);
        const float h2 = sigm(go) * tanhf(c2);
        out[V + dir * H + unit] = h2;               // new_hidden
        out[V + 2 * H + dir * H + unit] = c2;       // new_cell
    }
}

// Kernel 5: decoder logits = W_dec @ [h_f,h_b] + b_dec. One wave per row.
__global__ void k5_dec(const float* __restrict__ out_h, const float* __restrict__ W_dec,
                       const float* __restrict__ b_dec, float* __restrict__ logits) {
    const int r = (blockIdx.x * blockDim.x + threadIdx.x) >> 6;  // 0..127
    const int lane = threadIdx.x & 63;
    const float4* Wr = (const float4*)(W_dec + (size_t)r * (2 * H));
    const float4* hv = (const float4*)out_h;
    float acc = 0.f;
    #pragma unroll
    for (int k = 0; k < 16; ++k) {  // 1024 float4 = 4096 floats
        float4 w4 = Wr[lane + 64 * k], h4 = hv[lane + 64 * k];
        acc += w4.x * h4.x + w4.y * h4.y + w4.z * h4.z + w4.w * h4.w;
    }
    acc = wave_reduce(acc);
    if (lane == 0) logits[r] = acc + b_dec[r];
}

extern "C" void kernel_launch(void* const* d_in, const int* in_sizes, int n_in,
                              void* d_out, int out_size, void* d_ws, size_t ws_size,
                              hipStream_t stream) {
    const int*   inp    = (const int*)  d_in[0];
    const float* hidden = (const float*)d_in[1];
    const float* cell   = (const float*)d_in[2];
    const float* stack  = (const float*)d_in[3];
    const float* emb    = (const float*)d_in[4];
    const float* W_ctrl = (const float*)d_in[5];
    const float* b_ctrl = (const float*)d_in[6];
    const float* W_sin  = (const float*)d_in[7];
    const float* b_sin  = (const float*)d_in[8];
    const float* w_ih_f = (const float*)d_in[9];
    const float* w_hh_f = (const float*)d_in[10];
    const float* b_ih_f = (const float*)d_in[11];
    const float* b_hh_f = (const float*)d_in[12];
    const float* w_ih_b = (const float*)d_in[13];
    const float* w_hh_b = (const float*)d_in[14];
    const float* b_ih_b = (const float*)d_in[15];
    const float* b_hh_b = (const float*)d_in[16];
    const float* W_dec  = (const float*)d_in[17];
    const float* b_dec  = (const float*)d_in[18];

    float* out = (float*)d_out;
    float* ws  = (float*)d_ws;

    float* new_stack = out + V + 4 * H;      // offset 8320
    float* rnn_in    = ws + WS_RNNIN;

    // K1: ctrl + stack_in
    k1_ctrl_stackin<<<257, 256, 0, stream>>>(hidden, W_ctrl, b_ctrl, W_sin, b_sin, ws);
    // K2: stack update + rnn_in assembly (1024 stack blocks + 8 emb blocks)
    k2_stack<<<DEPTH + 8, 256, 0, stream>>>(stack, emb, inp, ws, new_stack, rnn_in);
    // K3: fused LSTM (gates + nonlinearity). 4096 waves, 1 per (dir, unit).
    k3_lstm<<<1024, 256, 0, stream>>>(rnn_in, hidden, cell,
                                      w_ih_f, w_hh_f, b_ih_f, b_hh_f,
                                      w_ih_b, w_hh_b, b_ih_b, b_hh_b, out);
    // K5: decoder, 128 rows, 1 wave/row
    k5_dec<<<32, 256, 0, stream>>>(out + V, W_dec, b_dec, out);
}

// Round 4
// 57.752 us; speedup vs baseline: 1.1068x; 1.0753x over previous
//
#include <hip/hip_runtime.h>
#include <math.h>

#define H 2048
#define Wd 256
#define DEPTH 1024
#define V 128

// ws float layout:
//  [0..2]   : a_push, a_pop, a_noop (softmaxed ctrl)
//  [4..259] : stack_in[256]
//  [320..2623] : rnn_in[2304]  (2048 emb || 256 stack_top)
#define WS_A      0
#define WS_SIN    4
#define WS_RNNIN  320

__device__ __forceinline__ float wave_reduce(float v) {
    #pragma unroll
    for (int off = 32; off; off >>= 1) v += __shfl_xor(v, off, 64);
    return v;
}

__device__ __forceinline__ float sigm(float x) { return 1.f / (1.f + expf(-x)); }

__device__ __forceinline__ float dot4(float4 a, float4 b) {
    return a.x * b.x + a.y * b.y + a.z * b.z + a.w * b.w;
}

// Kernel 1 (fused front): blocks 0..255 each compute the 3 ctrl dots
// redundantly (12 KB L2-hit reads per block), softmax locally, their W_sin
// row dot -> stack_in[r], and the blended stack_top -> rnn_in[H+r].
// Blocks 256..263 copy the embedding row into rnn_in[0..2047].
__global__ void k1_front(const float* __restrict__ hidden,
                         const float* __restrict__ stack,
                         const float* __restrict__ emb, const int* __restrict__ inp,
                         const float* __restrict__ W_ctrl, const float* __restrict__ b_ctrl,
                         const float* __restrict__ W_sin, const float* __restrict__ b_sin,
                         float* __restrict__ ws, float* __restrict__ rnn_in) {
    const int b = blockIdx.x;
    if (b >= 256) {
        const int j = (b - 256) * 256 + threadIdx.x;  // 0..2047
        rnn_in[j] = emb[(size_t)inp[0] * H + j];
        return;
    }
    __shared__ float dots[3];
    __shared__ float red[4];
    const int wave = threadIdx.x >> 6, lane = threadIdx.x & 63;
    const float4* hv = (const float4*)hidden;   // 1024 float4 = h2s

    if (wave < 3) {
        const float4* Wr = (const float4*)(W_ctrl + wave * (2 * H));
        float acc = 0.f;
        #pragma unroll
        for (int k = 0; k < 16; ++k) acc += dot4(Wr[lane + 64 * k], hv[lane + 64 * k]);
        acc = wave_reduce(acc);
        if (lane == 0) dots[wave] = acc + b_ctrl[wave];
    }

    // stack_in row dot: all 256 threads, 4 float4 each
    const int r = b;
    const float4* Ws = (const float4*)(W_sin + (size_t)r * (2 * H));
    float acc = 0.f;
    #pragma unroll
    for (int k = 0; k < 4; ++k) acc += dot4(Ws[threadIdx.x + 256 * k], hv[threadIdx.x + 256 * k]);
    acc = wave_reduce(acc);
    if (lane == 0) red[wave] = acc;
    __syncthreads();

    if (threadIdx.x == 0) {
        const float m = fmaxf(dots[0], fmaxf(dots[1], dots[2]));
        const float e0 = expf(dots[0] - m), e1 = expf(dots[1] - m), e2 = expf(dots[2] - m);
        const float s = e0 + e1 + e2;
        const float a_push = e0 / s, a_pop = e1 / s, a_noop = e2 / s;
        const float sin_r = tanhf(red[0] + red[1] + red[2] + red[3] + b_sin[r]);
        ws[WS_SIN + r] = sin_r;
        // stack_top[r] = new_stack[0][r]
        rnn_in[H + r] = a_noop * stack[r] + a_push * sin_r + a_pop * stack[Wd + r];
        if (r == 0) {
            ws[WS_A + 0] = a_push;
            ws[WS_A + 1] = a_pop;
            ws[WS_A + 2] = a_noop;
        }
    }
}

// Kernel 3: fused LSTM, one wave per (dir, unit). x/h vectors staged fully in
// registers; weight chunks staged 18-deep (2 gates x 9 chunks) with
// sched_barrier(0) pinning so the scheduler cannot sink the loads back into
// the FMA stream (R2 showed unpinned staging gets re-associated, VGPR 36).
__global__ void __launch_bounds__(256, 3) k3_lstm(
        const float* __restrict__ rnn_in, const float* __restrict__ hidden,
        const float* __restrict__ cell,
        const float* __restrict__ w_ih_f, const float* __restrict__ w_hh_f,
        const float* __restrict__ b_ih_f, const float* __restrict__ b_hh_f,
        const float* __restrict__ w_ih_b, const float* __restrict__ w_hh_b,
        const float* __restrict__ b_ih_b, const float* __restrict__ b_hh_b,
        float* __restrict__ out) {
    const int wid = (blockIdx.x * blockDim.x + threadIdx.x) >> 6;  // 0..4095
    const int lane = threadIdx.x & 63;
    const int dir = wid >> 11;          // 0 = fwd, 1 = bwd
    const int unit = wid & (H - 1);     // 0..2047

    const float* wih = dir ? w_ih_b : w_ih_f;
    const float* whh = dir ? w_hh_b : w_hh_f;
    const float* bih = dir ? b_ih_b : b_ih_f;
    const float* bhh = dir ? b_hh_b : b_hh_f;

    const float4* xi = (const float4*)rnn_in;
    const float4* hv = (const float4*)(hidden + dir * H);

    const float4* wi_i = (const float4*)wih + (size_t)unit * 576;
    const float4* wi_f = (const float4*)wih + (size_t)(H + unit) * 576;
    const float4* wi_g = (const float4*)wih + (size_t)(2 * H + unit) * 576;
    const float4* wi_o = (const float4*)wih + (size_t)(3 * H + unit) * 576;
    const float4* wh_i = (const float4*)whh + (size_t)unit * 512;
    const float4* wh_f = (const float4*)whh + (size_t)(H + unit) * 512;
    const float4* wh_g = (const float4*)whh + (size_t)(2 * H + unit) * 512;
    const float4* wh_o = (const float4*)whh + (size_t)(3 * H + unit) * 512;

    // Stage the shared x vector (L1/L2-hit) once: 9 float4 = 36 VGPR.
    float4 xr[9];
    #pragma unroll
    for (int k = 0; k < 9; ++k) xr[k] = xi[lane + 64 * k];

    float ai = 0.f, af = 0.f, ag = 0.f, ao = 0.f;
    float4 wa[9], wb[9];

    // --- x-part, gates i,f: 18 loads in flight ---
    #pragma unroll
    for (int k = 0; k < 9; ++k) { wa[k] = wi_i[lane + 64 * k]; wb[k] = wi_f[lane + 64 * k]; }
    __builtin_amdgcn_sched_barrier(0);
    #pragma unroll
    for (int k = 0; k < 9; ++k) { ai += dot4(wa[k], xr[k]); af += dot4(wb[k], xr[k]); }

    // --- x-part, gates g,o ---
    #pragma unroll
    for (int k = 0; k < 9; ++k) { wa[k] = wi_g[lane + 64 * k]; wb[k] = wi_o[lane + 64 * k]; }
    __builtin_amdgcn_sched_barrier(0);
    #pragma unroll
    for (int k = 0; k < 9; ++k) { ag += dot4(wa[k], xr[k]); ao += dot4(wb[k], xr[k]); }

    // Stage the shared h vector: 8 float4.
    float4 hr[8];
    #pragma unroll
    for (int k = 0; k < 8; ++k) hr[k] = hv[lane + 64 * k];

    // --- h-part, gates i,f ---
    #pragma unroll
    for (int k = 0; k < 8; ++k) { wa[k] = wh_i[lane + 64 * k]; wb[k] = wh_f[lane + 64 * k]; }
    __builtin_amdgcn_sched_barrier(0);
    #pragma unroll
    for (int k = 0; k < 8; ++k) { ai += dot4(wa[k], hr[k]); af += dot4(wb[k], hr[k]); }

    // --- h-part, gates g,o ---
    #pragma unroll
    for (int k = 0; k < 8; ++k) { wa[k] = wh_g[lane + 64 * k]; wb[k] = wh_o[lane + 64 * k]; }
    __builtin_amdgcn_sched_barrier(0);
    #pragma unroll
    for (int k = 0; k < 8; ++k) { ag += dot4(wa[k], hr[k]); ao += dot4(wb[k], hr[k]); }

    ai = wave_reduce(ai);
    af = wave_reduce(af);
    ag = wave_reduce(ag);
    ao = wave_reduce(ao);

    if (lane == 0) {
        const float gi = ai + bih[unit]         + bhh[unit];
        const float gf = af + bih[H + unit]     + bhh[H + unit];
        const float gg = ag + bih[2 * H + unit] + bhh[2 * H + unit];
        const float go = ao + bih[3 * H + unit] + bhh[3 * H + unit];
        const float c_old = cell[dir * H + unit];
        const float c2 = sigm(gf) * c_old + sigm(gi) * tanhf(gg);
        const float h2 = sigm(go) * tanhf(c2);
        out[V + dir * H + unit] = h2;               // new_hidden
        out[V + 2 * H + dir * H + unit] = c2;       // new_cell
    }
}

// Kernel 5 (fused back): blocks 0..1023 do the stack blend (independent of
// the LSTM, moved here to cut a launch); blocks 1024..1055 are the decoder
// (one wave per logit row).
__global__ void k5_back(const float* __restrict__ stack, const float* __restrict__ ws,
                        const float* __restrict__ W_dec, const float* __restrict__ b_dec,
                        float* __restrict__ out) {
    const int b = blockIdx.x;
    if (b < DEPTH) {
        const int d = b, w = threadIdx.x;
        const float a_push = ws[WS_A + 0];
        const float a_pop  = ws[WS_A + 1];
        const float a_noop = ws[WS_A + 2];
        const float cur  = stack[d * Wd + w];
        const float up   = (d == 0) ? ws[WS_SIN + w] : stack[(d - 1) * Wd + w];
        const float down = (d == DEPTH - 1) ? 0.f : stack[(d + 1) * Wd + w];
        out[V + 4 * H + d * Wd + w] = a_noop * cur + a_push * up + a_pop * down;
    } else {
        const int r = ((b - DEPTH) * 256 + threadIdx.x) >> 6;  // 0..127
        const int lane = threadIdx.x & 63;
        const float4* Wr = (const float4*)(W_dec + (size_t)r * (2 * H));
        const float4* hv = (const float4*)(out + V);
        float acc = 0.f;
        #pragma unroll
        for (int k = 0; k < 16; ++k) acc += dot4(Wr[lane + 64 * k], hv[lane + 64 * k]);
        acc = wave_reduce(acc);
        if (lane == 0) out[r] = acc + b_dec[r];
    }
}

extern "C" void kernel_launch(void* const* d_in, const int* in_sizes, int n_in,
                              void* d_out, int out_size, void* d_ws, size_t ws_size,
                              hipStream_t stream) {
    const int*   inp    = (const int*)  d_in[0];
    const float* hidden = (const float*)d_in[1];
    const float* cell   = (const float*)d_in[2];
    const float* stack  = (const float*)d_in[3];
    const float* emb    = (const float*)d_in[4];
    const float* W_ctrl = (const float*)d_in[5];
    const float* b_ctrl = (const float*)d_in[6];
    const float* W_sin  = (const float*)d_in[7];
    const float* b_sin  = (const float*)d_in[8];
    const float* w_ih_f = (const float*)d_in[9];
    const float* w_hh_f = (const float*)d_in[10];
    const float* b_ih_f = (const float*)d_in[11];
    const float* b_hh_f = (const float*)d_in[12];
    const float* w_ih_b = (const float*)d_in[13];
    const float* w_hh_b = (const float*)d_in[14];
    const float* b_ih_b = (const float*)d_in[15];
    const float* b_hh_b = (const float*)d_in[16];
    const float* W_dec  = (const float*)d_in[17];
    const float* b_dec  = (const float*)d_in[18];

    float* out = (float*)d_out;
    float* ws  = (float*)d_ws;
    float* rnn_in = ws + WS_RNNIN;

    // K1: ctrl + stack_in + rnn_in assembly (one kernel)
    k1_front<<<264, 256, 0, stream>>>(hidden, stack, emb, inp,
                                      W_ctrl, b_ctrl, W_sin, b_sin, ws, rnn_in);
    // K3: fused LSTM (gates + nonlinearity). 4096 waves, 1 per (dir, unit).
    k3_lstm<<<1024, 256, 0, stream>>>(rnn_in, hidden, cell,
                                      w_ih_f, w_hh_f, b_ih_f, b_hh_f,
                                      w_ih_b, w_hh_b, b_ih_b, b_hh_b, out);
    // K5: stack blend + decoder (one kernel)
    k5_back<<<DEPTH + 32, 256, 0, stream>>>(stack, ws, W_dec, b_dec, out);
}